// Round 1
// baseline (275.508 us; speedup 1.0000x reference)
//
#include <hip/hip_runtime.h>
#include <hip/hip_bf16.h>
#include <stdint.h>

typedef short short8 __attribute__((ext_vector_type(8)));
typedef float floatx4 __attribute__((ext_vector_type(4)));

#define AS1 __attribute__((address_space(1)))
#define AS3 __attribute__((address_space(3)))
#define DEV static __device__ __forceinline__

DEV uint16_t f2bf(float x) {
  union { float f; uint32_t u; } v; v.f = x;
  return (uint16_t)((v.u + 0x7fffu + ((v.u >> 16) & 1u)) >> 16);
}

// ---------------- prep kernels ----------------

// fp32 -> bf16 cast, 4 elems/thread
__global__ __launch_bounds__(256) void cvt_bf16_k(const float* __restrict__ src,
                                                  uint16_t* __restrict__ dst, int n4) {
  int i = blockIdx.x * 256 + threadIdx.x;
  if (i >= n4) return;
  float4 v = ((const float4*)src)[i];
  union { uint16_t u[4]; uint64_t q; } o;
  o.u[0] = f2bf(v.x); o.u[1] = f2bf(v.y); o.u[2] = f2bf(v.z); o.u[3] = f2bf(v.w);
  ((uint64_t*)dst)[i] = o.q;
}

// WqFT[j][k] = sum_{r<4} Wq[k][128*(j>>5)+4*(j&31)+r]   (j<512, k<2048), bf16, transposed store
__global__ __launch_bounds__(256) void fold_wq_t_k(const float* __restrict__ Wq,
                                                   uint16_t* __restrict__ WqFT) {
  __shared__ float tile[32][33];
  const int t = threadIdx.x;
  const int j0 = (blockIdx.x / 64) * 32, k0 = (blockIdx.x % 64) * 32;
  {
    const int tj = t & 31, tk8 = t >> 5;
    const int j = j0 + tj;
    const int base = 128 * (j >> 5) + 4 * (j & 31);
    for (int kk = 0; kk < 4; ++kk) {
      int kl = tk8 * 4 + kk;
      float4 w = *(const float4*)(Wq + (size_t)(k0 + kl) * 2048 + base);
      tile[tj][kl] = w.x + w.y + w.z + w.w;
    }
  }
  __syncthreads();
  {
    const int tk = t & 31, tj8 = t >> 5;
    for (int jj = 0; jj < 4; ++jj) {
      int jl = tj8 * 4 + jj;
      WqFT[(size_t)(j0 + jl) * 2048 + k0 + tk] = f2bf(tile[jl][tk]);
    }
  }
}

// WkvT[j][k] = (j<512 ? Wk[k][j] : Wv[k][j-512]), bf16 transposed, j<1024, k<2048
__global__ __launch_bounds__(256) void wkv_t_k(const float* __restrict__ Wk,
                                               const float* __restrict__ Wv,
                                               uint16_t* __restrict__ WkvT) {
  __shared__ float tile[32][33];
  const int t = threadIdx.x;
  const int j0 = (blockIdx.x / 64) * 32, k0 = (blockIdx.x % 64) * 32;
  const float* src = (j0 < 512) ? Wk : Wv;
  const int jb = (j0 < 512) ? j0 : j0 - 512;
  {
    const int tj = t & 31, tk8 = t >> 5;
    for (int kk = 0; kk < 4; ++kk) {
      int kl = tk8 * 4 + kk;
      tile[tj][kl] = src[(size_t)(k0 + kl) * 512 + jb + tj];
    }
  }
  __syncthreads();
  {
    const int tk = t & 31, tj8 = t >> 5;
    for (int jj = 0; jj < 4; ++jj) {
      int jl = tj8 * 4 + jj;
      WkvT[(size_t)(j0 + jl) * 2048 + k0 + tk] = f2bf(tile[jl][tk]);
    }
  }
}

// WoFT[n][j] = sum_{r<4} Wo[128*(j>>5)+4*(j&31)+r][n]  (n<2048, j<512), bf16 transposed
__global__ __launch_bounds__(256) void wof_t_k(const float* __restrict__ Wo,
                                               uint16_t* __restrict__ WoFT) {
  __shared__ float tile[32][33]; // [n-local][j-local]
  const int t = threadIdx.x;
  const int n0 = (blockIdx.x / 16) * 32, j0 = (blockIdx.x % 16) * 32;
  {
    const int tn = t & 31, tj8 = t >> 5;
    for (int jj = 0; jj < 4; ++jj) {
      int jl = tj8 * 4 + jj;
      int j = j0 + jl;
      int base = 128 * (j >> 5) + 4 * (j & 31);
      float ssum = 0.f;
      for (int r = 0; r < 4; ++r) ssum += Wo[(size_t)(base + r) * 2048 + n0 + tn];
      tile[tn][jl] = ssum;
    }
  }
  __syncthreads();
  {
    const int tj = t & 31, tn8 = t >> 5;
    for (int nn = 0; nn < 4; ++nn) {
      int nl = tn8 * 4 + nn;
      WoFT[(size_t)(n0 + nl) * 512 + j0 + tj] = f2bf(tile[nl][tj]);
    }
  }
}

// biasT[k][q] = (1/mask[q][k] - 1) * log2(e), fp32 transposed
__global__ __launch_bounds__(256) void bias_t_k(const float* __restrict__ mask,
                                                float* __restrict__ biasT) {
  __shared__ float tile[32][33]; // [k-local][q-local]
  const int t = threadIdx.x;
  const int k0 = (blockIdx.x / 64) * 32, q0 = (blockIdx.x % 64) * 32;
  {
    const int tk = t & 31, tq8 = t >> 5;
    for (int qq = 0; qq < 4; ++qq) {
      int ql = tq8 * 4 + qq;
      tile[tk][ql] = mask[(size_t)(q0 + ql) * 2048 + k0 + tk];
    }
  }
  __syncthreads();
  {
    const int tq = t & 31, tk8 = t >> 5;
    for (int kk = 0; kk < 4; ++kk) {
      int kl = tk8 * 4 + kk;
      float mv = tile[kl][tq];
      biasT[(size_t)(k0 + kl) * 2048 + q0 + tq] = (1.0f / mv - 1.0f) * 1.4426950408889634f;
    }
  }
}

// VT[b][f][k] = XKV[b][k][512+f]  (f<512, k<2048), bf16 transpose
__global__ __launch_bounds__(256) void v_transpose_k(const uint16_t* __restrict__ XKV,
                                                     uint16_t* __restrict__ VT) {
  __shared__ uint16_t tile[32][34];
  const int t = threadIdx.x;
  const int b = blockIdx.x >> 10;
  const int rem = blockIdx.x & 1023;
  const int f0 = (rem / 64) * 32, k0 = (rem % 64) * 32;
  {
    const int tf = t & 31, tk8 = t >> 5;
    for (int kk = 0; kk < 4; ++kk) {
      int kl = tk8 * 4 + kk;
      tile[tf][kl] = XKV[(size_t)(b * 2048 + k0 + kl) * 1024 + 512 + f0 + tf];
    }
  }
  __syncthreads();
  {
    const int tk = t & 31, tf8 = t >> 5;
    for (int ff = 0; ff < 4; ++ff) {
      int fl = tf8 * 4 + ff;
      VT[(size_t)(b * 512 + f0 + fl) * 2048 + k0 + tk] = tile[fl][tk];
    }
  }
}

// ---------------- bf16 GEMM: C[M,N] = A[M,K] @ BT[N,K]^T ----------------
// m97-style: 128x64 tile, BK=64, global_load_lds staging, 4 waves.
template <typename OutT>
__global__ __launch_bounds__(256) void gemm_bt(const uint16_t* __restrict__ A,
                                               const uint16_t* __restrict__ BT,
                                               OutT* __restrict__ C, int M, int N, int K) {
  constexpr int BM = 128, BN = 64, BK = 64;
  __shared__ uint16_t As[BM * BK];
  __shared__ uint16_t Bs[BN * BK];
  const int nbn = N / BN;
  const int m0 = (blockIdx.x / nbn) * BM;
  const int n0 = (blockIdx.x % nbn) * BN;
  const int lane = threadIdx.x & 63, wave = threadIdx.x >> 6;
  const int lo = lane & 15, g = lane >> 4;
  const int wm = wave >> 1, wn = wave & 1;
  floatx4 acc[4][2] = {};

  for (int k0 = 0; k0 < K; k0 += BK) {
    // stage A tile: 1024 16B chunks, 4 per thread
    for (int c = 0; c < 4; ++c) {
      int chunk = wave * 256 + c * 64 + lane;
      int row = chunk >> 3, col = (chunk & 7) * 8;
      const uint16_t* gp = A + (size_t)(m0 + row) * K + k0 + col;
      __builtin_amdgcn_global_load_lds((const AS1 uint32_t*)gp,
                                       (AS3 uint32_t*)(As + (size_t)(wave * 256 + c * 64) * 8),
                                       16, 0, 0);
    }
    // stage BT tile: 512 chunks, 2 per thread
    for (int c = 0; c < 2; ++c) {
      int chunk = wave * 128 + c * 64 + lane;
      int row = chunk >> 3, col = (chunk & 7) * 8;
      const uint16_t* gp = BT + (size_t)(n0 + row) * K + k0 + col;
      __builtin_amdgcn_global_load_lds((const AS1 uint32_t*)gp,
                                       (AS3 uint32_t*)(Bs + (size_t)(wave * 128 + c * 64) * 8),
                                       16, 0, 0);
    }
    __syncthreads();
#pragma unroll
    for (int kk = 0; kk < BK; kk += 32) {
      short8 af[4], bf[2];
#pragma unroll
      for (int fa = 0; fa < 4; ++fa)
        af[fa] = *(const short8*)&As[(wm * 64 + fa * 16 + lo) * BK + kk + g * 8];
#pragma unroll
      for (int fb = 0; fb < 2; ++fb)
        bf[fb] = *(const short8*)&Bs[(wn * 32 + fb * 16 + lo) * BK + kk + g * 8];
#pragma unroll
      for (int fa = 0; fa < 4; ++fa)
#pragma unroll
        for (int fb = 0; fb < 2; ++fb)
          acc[fa][fb] = __builtin_amdgcn_mfma_f32_16x16x32_bf16(af[fa], bf[fb], acc[fa][fb], 0, 0, 0);
    }
    __syncthreads();
  }
#pragma unroll
  for (int fa = 0; fa < 4; ++fa)
#pragma unroll
    for (int fb = 0; fb < 2; ++fb)
#pragma unroll
      for (int r = 0; r < 4; ++r) {
        int row = m0 + wm * 64 + fa * 16 + g * 4 + r;
        int col = n0 + wn * 32 + fb * 16 + lo;
        if constexpr (sizeof(OutT) == 2)
          C[(size_t)row * N + col] = (OutT)f2bf(acc[fa][fb][r]);
        else
          C[(size_t)row * N + col] = (OutT)acc[fa][fb][r];
      }
}

// ---------------- flash attention, d_eff = 32 ----------------
// 1 wave per block; 16 q-rows/wave; swapped-operand QK^T (S^T) so softmax is lane-local.
__global__ __launch_bounds__(64) void attn_k(const uint16_t* __restrict__ Qf,
                                             const uint16_t* __restrict__ XKV,
                                             const uint16_t* __restrict__ VT,
                                             const float* __restrict__ biasT,
                                             uint16_t* __restrict__ O32) {
  const int l = threadIdx.x, lo = l & 15, g = l >> 4;
  const int qt = blockIdx.x & 127, bh = blockIdx.x >> 7;
  const int h = bh & 15, b = bh >> 4;
  const int q0 = qt * 16;
  const float SCALE2 = 0.08838834764831845f * 1.4426950408889634f; // 1/sqrt(128)*log2(e)

  short8 qf = *(const short8*)(Qf + ((size_t)(b * 2048 + q0 + lo)) * 512 + h * 32 + g * 8);
  const uint16_t* Kp = XKV + (size_t)(b * 2048) * 1024 + h * 32 + g * 8;
  const uint16_t* Vp = VT + ((size_t)(b * 512 + h * 32 + lo)) * 2048 + g * 8;
  const float* Bp = biasT + q0 + lo;

  float m = -1e30f, s = 0.f;
  floatx4 acc0 = {0.f, 0.f, 0.f, 0.f}, acc1 = {0.f, 0.f, 0.f, 0.f};
  const floatx4 zf = {0.f, 0.f, 0.f, 0.f};
  __shared__ uint32_t plds[16][20]; // padded: row stride 80B, 16B-aligned reads

  for (int k0 = 0; k0 < 2048; k0 += 32) {
    short8 kf0 = *(const short8*)(Kp + (size_t)(k0 + lo) * 1024);
    short8 kf1 = *(const short8*)(Kp + (size_t)(k0 + 16 + lo) * 1024);
    floatx4 s0 = __builtin_amdgcn_mfma_f32_16x16x32_bf16(kf0, qf, zf, 0, 0, 0);
    floatx4 s1 = __builtin_amdgcn_mfma_f32_16x16x32_bf16(kf1, qf, zf, 0, 0, 0);
#pragma unroll
    for (int r = 0; r < 4; ++r) {
      s0[r] = s0[r] * SCALE2 - Bp[(size_t)(k0 + g * 4 + r) * 2048];
      s1[r] = s1[r] * SCALE2 - Bp[(size_t)(k0 + 16 + g * 4 + r) * 2048];
    }
    float tm = fmaxf(fmaxf(fmaxf(s0[0], s0[1]), fmaxf(s0[2], s0[3])),
                     fmaxf(fmaxf(s1[0], s1[1]), fmaxf(s1[2], s1[3])));
    tm = fmaxf(tm, __shfl_xor(tm, 16));
    tm = fmaxf(tm, __shfl_xor(tm, 32));
    float mn = fmaxf(m, tm);
    float f = __builtin_amdgcn_exp2f(m - mn);
    float p0[4], p1[4];
    float ts = 0.f;
#pragma unroll
    for (int r = 0; r < 4; ++r) {
      p0[r] = __builtin_amdgcn_exp2f(s0[r] - mn);
      p1[r] = __builtin_amdgcn_exp2f(s1[r] - mn);
      ts += p0[r] + p1[r];
    }
    ts += __shfl_xor(ts, 16);
    ts += __shfl_xor(ts, 32);
    s = s * f + ts;
    m = mn;
#pragma unroll
    for (int r = 0; r < 4; ++r) { acc0[r] *= f; acc1[r] *= f; }
    __syncthreads();
    plds[lo][g * 2 + 0] = (uint32_t)f2bf(p0[0]) | ((uint32_t)f2bf(p0[1]) << 16);
    plds[lo][g * 2 + 1] = (uint32_t)f2bf(p0[2]) | ((uint32_t)f2bf(p0[3]) << 16);
    plds[lo][g * 2 + 8] = (uint32_t)f2bf(p1[0]) | ((uint32_t)f2bf(p1[1]) << 16);
    plds[lo][g * 2 + 9] = (uint32_t)f2bf(p1[2]) | ((uint32_t)f2bf(p1[3]) << 16);
    __syncthreads();
    short8 pf = *(const short8*)((const uint16_t*)&plds[lo][0] + g * 8);
    short8 v0 = *(const short8*)(Vp + k0);
    short8 v1 = *(const short8*)(Vp + 16 * 2048 + k0);
    acc0 = __builtin_amdgcn_mfma_f32_16x16x32_bf16(v0, pf, acc0, 0, 0, 0);
    acc1 = __builtin_amdgcn_mfma_f32_16x16x32_bf16(v1, pf, acc1, 0, 0, 0);
  }
  float inv = 1.0f / s;
  uint16_t* Op = O32 + ((size_t)(b * 2048 + q0 + lo)) * 512 + h * 32;
#pragma unroll
  for (int r = 0; r < 4; ++r) {
    Op[g * 4 + r] = f2bf(acc0[r] * inv);
    Op[16 + g * 4 + r] = f2bf(acc1[r] * inv);
  }
}

// ---------------- launch ----------------
extern "C" void kernel_launch(void* const* d_in, const int* in_sizes, int n_in,
                              void* d_out, int out_size, void* d_ws, size_t ws_size,
                              hipStream_t stream) {
  const float* q    = (const float*)d_in[0];
  const float* kv   = (const float*)d_in[1];
  const float* mask = (const float*)d_in[2];
  const float* Wq   = (const float*)d_in[3];
  const float* Wk   = (const float*)d_in[4];
  const float* Wv   = (const float*)d_in[5];
  const float* Wo   = (const float*)d_in[6];

  char* ws = (char*)d_ws;
  uint16_t* qb    = (uint16_t*)(ws);
  uint16_t* kvb   = (uint16_t*)(ws + (16ull << 20));
  uint16_t* Qf    = (uint16_t*)(ws + (32ull << 20));
  uint16_t* XKV   = (uint16_t*)(ws + (36ull << 20));
  uint16_t* VT    = (uint16_t*)(ws + (44ull << 20));
  uint16_t* O32   = (uint16_t*)(ws + (48ull << 20));
  uint16_t* WqFT  = (uint16_t*)(ws + (52ull << 20));
  uint16_t* WkvT  = (uint16_t*)(ws + (54ull << 20));
  uint16_t* WoFT  = (uint16_t*)(ws + (58ull << 20));
  float*    biasT = (float*)   (ws + (60ull << 20));

  cvt_bf16_k<<<8192, 256, 0, stream>>>(q, qb, 2097152);
  cvt_bf16_k<<<8192, 256, 0, stream>>>(kv, kvb, 2097152);
  fold_wq_t_k<<<1024, 256, 0, stream>>>(Wq, WqFT);
  wkv_t_k<<<2048, 256, 0, stream>>>(Wk, Wv, WkvT);
  wof_t_k<<<1024, 256, 0, stream>>>(Wo, WoFT);
  bias_t_k<<<4096, 256, 0, stream>>>(mask, biasT);

  gemm_bt<uint16_t><<<(4096 / 128) * (512 / 64), 256, 0, stream>>>(qb, WqFT, Qf, 4096, 512, 2048);
  gemm_bt<uint16_t><<<(4096 / 128) * (1024 / 64), 256, 0, stream>>>(kvb, WkvT, XKV, 4096, 1024, 2048);
  v_transpose_k<<<2048, 256, 0, stream>>>(XKV, VT);
  attn_k<<<4096, 64, 0, stream>>>(Qf, XKV, VT, biasT, O32);
  gemm_bt<float><<<(4096 / 128) * (2048 / 64), 256, 0, stream>>>(O32, WoFT, (float*)d_out, 4096, 2048, 512);
}

// Round 3
// 207.682 us; speedup vs baseline: 1.3266x; 1.3266x over previous
//
#include <hip/hip_runtime.h>
#include <hip/hip_bf16.h>
#include <stdint.h>

typedef short short8 __attribute__((ext_vector_type(8)));
typedef float floatx4 __attribute__((ext_vector_type(4)));

#define AS1 __attribute__((address_space(1)))
#define AS3 __attribute__((address_space(3)))
#define DEV static __device__ __forceinline__

DEV uint16_t f2bf(float x) {
  union { float f; uint32_t u; } v; v.f = x;
  return (uint16_t)((v.u + 0x7fffu + ((v.u >> 16) & 1u)) >> 16);
}

DEV uint32_t cvtpk(float a, float b) {
  uint32_t r;
  asm("v_cvt_pk_bf16_f32 %0, %1, %2" : "=v"(r) : "v"(a), "v"(b));
  return r;
}

// ---------------- prep kernels ----------------

__global__ __launch_bounds__(256) void cvt_bf16_k(const float* __restrict__ src,
                                                  uint16_t* __restrict__ dst, int n4) {
  int i = blockIdx.x * 256 + threadIdx.x;
  if (i >= n4) return;
  float4 v = ((const float4*)src)[i];
  union { uint16_t u[4]; uint64_t q; } o;
  o.u[0] = f2bf(v.x); o.u[1] = f2bf(v.y); o.u[2] = f2bf(v.z); o.u[3] = f2bf(v.w);
  ((uint64_t*)dst)[i] = o.q;
}

// WqFT[j][k] = sum_{r<4} Wq[k][128*(j>>5)+4*(j&31)+r]   (j<512, k<2048), bf16 transposed
__global__ __launch_bounds__(256) void fold_wq_t_k(const float* __restrict__ Wq,
                                                   uint16_t* __restrict__ WqFT) {
  __shared__ float tile[32][33];
  const int t = threadIdx.x;
  const int j0 = (blockIdx.x / 64) * 32, k0 = (blockIdx.x % 64) * 32;
  {
    const int tj = t & 31, tk8 = t >> 5;
    const int j = j0 + tj;
    const int base = 128 * (j >> 5) + 4 * (j & 31);
    for (int kk = 0; kk < 4; ++kk) {
      int kl = tk8 * 4 + kk;
      float4 w = *(const float4*)(Wq + (size_t)(k0 + kl) * 2048 + base);
      tile[tj][kl] = w.x + w.y + w.z + w.w;
    }
  }
  __syncthreads();
  {
    const int tk = t & 31, tj8 = t >> 5;
    for (int jj = 0; jj < 4; ++jj) {
      int jl = tj8 * 4 + jj;
      WqFT[(size_t)(j0 + jl) * 2048 + k0 + tk] = f2bf(tile[jl][tk]);
    }
  }
}

__global__ __launch_bounds__(256) void wkv_t_k(const float* __restrict__ Wk,
                                               const float* __restrict__ Wv,
                                               uint16_t* __restrict__ WkvT) {
  __shared__ float tile[32][33];
  const int t = threadIdx.x;
  const int j0 = (blockIdx.x / 64) * 32, k0 = (blockIdx.x % 64) * 32;
  const float* src = (j0 < 512) ? Wk : Wv;
  const int jb = (j0 < 512) ? j0 : j0 - 512;
  {
    const int tj = t & 31, tk8 = t >> 5;
    for (int kk = 0; kk < 4; ++kk) {
      int kl = tk8 * 4 + kk;
      tile[tj][kl] = src[(size_t)(k0 + kl) * 512 + jb + tj];
    }
  }
  __syncthreads();
  {
    const int tk = t & 31, tj8 = t >> 5;
    for (int jj = 0; jj < 4; ++jj) {
      int jl = tj8 * 4 + jj;
      WkvT[(size_t)(j0 + jl) * 2048 + k0 + tk] = f2bf(tile[jl][tk]);
    }
  }
}

__global__ __launch_bounds__(256) void wof_t_k(const float* __restrict__ Wo,
                                               uint16_t* __restrict__ WoFT) {
  __shared__ float tile[32][33];
  const int t = threadIdx.x;
  const int n0 = (blockIdx.x / 16) * 32, j0 = (blockIdx.x % 16) * 32;
  {
    const int tn = t & 31, tj8 = t >> 5;
    for (int jj = 0; jj < 4; ++jj) {
      int jl = tj8 * 4 + jj;
      int j = j0 + jl;
      int base = 128 * (j >> 5) + 4 * (j & 31);
      float ssum = 0.f;
      for (int r = 0; r < 4; ++r) ssum += Wo[(size_t)(base + r) * 2048 + n0 + tn];
      tile[tn][jl] = ssum;
    }
  }
  __syncthreads();
  {
    const int tj = t & 31, tn8 = t >> 5;
    for (int nn = 0; nn < 4; ++nn) {
      int nl = tn8 * 4 + nn;
      WoFT[(size_t)(n0 + nl) * 512 + j0 + tj] = f2bf(tile[nl][tj]);
    }
  }
}

// mask triviality flag
__global__ void flag_init_k(uint32_t* f) {
  if (threadIdx.x == 0 && blockIdx.x == 0) *f = 1u;
}
__global__ __launch_bounds__(256) void mask_scan_k(const float* __restrict__ mask,
                                                   uint32_t* __restrict__ f) {
  int i = blockIdx.x * 256 + threadIdx.x;
  const float4* p = (const float4*)mask;
  float4 a = p[i * 2], b = p[i * 2 + 1];
  bool bad = (a.x != 1.f) | (a.y != 1.f) | (a.z != 1.f) | (a.w != 1.f) |
             (b.x != 1.f) | (b.y != 1.f) | (b.z != 1.f) | (b.w != 1.f);
  if (bad) *f = 0u;
}

// VT[b][f][k] = XKV[b][k][512+f]  (f<512, k<2048), bf16 transpose
__global__ __launch_bounds__(256) void v_transpose_k(const uint16_t* __restrict__ XKV,
                                                     uint16_t* __restrict__ VT) {
  __shared__ uint16_t tile[32][34];
  const int t = threadIdx.x;
  const int b = blockIdx.x >> 10;
  const int rem = blockIdx.x & 1023;
  const int f0 = (rem / 64) * 32, k0 = (rem % 64) * 32;
  {
    const int tf = t & 31, tk8 = t >> 5;
    for (int kk = 0; kk < 4; ++kk) {
      int kl = tk8 * 4 + kk;
      tile[tf][kl] = XKV[(size_t)(b * 2048 + k0 + kl) * 1024 + 512 + f0 + tf];
    }
  }
  __syncthreads();
  {
    const int tk = t & 31, tf8 = t >> 5;
    for (int ff = 0; ff < 4; ++ff) {
      int fl = tf8 * 4 + ff;
      VT[(size_t)(b * 512 + f0 + fl) * 2048 + k0 + tk] = tile[fl][tk];
    }
  }
}

// ---------------- bf16 GEMM: C[M,N] = A[M,K] @ BT[N,K]^T (optional epilogue scale) ---
template <typename OutT>
__global__ __launch_bounds__(256) void gemm_bt(const uint16_t* __restrict__ A,
                                               const uint16_t* __restrict__ BT,
                                               OutT* __restrict__ C, int M, int N, int K,
                                               float scale) {
  constexpr int BM = 128, BN = 64, BK = 64;
  __shared__ __attribute__((aligned(16))) uint16_t As[BM * BK];
  __shared__ __attribute__((aligned(16))) uint16_t Bs[BN * BK];
  const int nbn = N / BN;
  const int m0 = (blockIdx.x / nbn) * BM;
  const int n0 = (blockIdx.x % nbn) * BN;
  const int lane = threadIdx.x & 63, wave = threadIdx.x >> 6;
  const int lo = lane & 15, g = lane >> 4;
  const int wm = wave >> 1, wn = wave & 1;
  floatx4 acc[4][2] = {};

  for (int k0 = 0; k0 < K; k0 += BK) {
    for (int c = 0; c < 4; ++c) {
      int chunk = wave * 256 + c * 64 + lane;
      int row = chunk >> 3, col = (chunk & 7) * 8;
      const uint16_t* gp = A + (size_t)(m0 + row) * K + k0 + col;
      __builtin_amdgcn_global_load_lds((const AS1 uint32_t*)gp,
                                       (AS3 uint32_t*)(As + (size_t)(wave * 256 + c * 64) * 8),
                                       16, 0, 0);
    }
    for (int c = 0; c < 2; ++c) {
      int chunk = wave * 128 + c * 64 + lane;
      int row = chunk >> 3, col = (chunk & 7) * 8;
      const uint16_t* gp = BT + (size_t)(n0 + row) * K + k0 + col;
      __builtin_amdgcn_global_load_lds((const AS1 uint32_t*)gp,
                                       (AS3 uint32_t*)(Bs + (size_t)(wave * 128 + c * 64) * 8),
                                       16, 0, 0);
    }
    __syncthreads();
#pragma unroll
    for (int kk = 0; kk < BK; kk += 32) {
      short8 af[4], bf[2];
#pragma unroll
      for (int fa = 0; fa < 4; ++fa)
        af[fa] = *(const short8*)&As[(wm * 64 + fa * 16 + lo) * BK + kk + g * 8];
#pragma unroll
      for (int fb = 0; fb < 2; ++fb)
        bf[fb] = *(const short8*)&Bs[(wn * 32 + fb * 16 + lo) * BK + kk + g * 8];
#pragma unroll
      for (int fa = 0; fa < 4; ++fa)
#pragma unroll
        for (int fb = 0; fb < 2; ++fb)
          acc[fa][fb] = __builtin_amdgcn_mfma_f32_16x16x32_bf16(af[fa], bf[fb], acc[fa][fb], 0, 0, 0);
    }
    __syncthreads();
  }
#pragma unroll
  for (int fa = 0; fa < 4; ++fa)
#pragma unroll
    for (int fb = 0; fb < 2; ++fb)
#pragma unroll
      for (int r = 0; r < 4; ++r) {
        int row = m0 + wm * 64 + fa * 16 + g * 4 + r;
        int col = n0 + wn * 32 + fb * 16 + lo;
        if constexpr (sizeof(OutT) == 2)
          C[(size_t)row * N + col] = (OutT)f2bf(acc[fa][fb][r] * scale);
        else
          C[(size_t)row * N + col] = (OutT)(acc[fa][fb][r] * scale);
      }
}

// ---------------- flash attention, d_eff = 32, 4 waves/block, LDS-staged K/V --------
// Qf is pre-scaled by (1/sqrt(128))*log2(e). S^T via mfma(K,Q); P redistributed to the
// PV B-fragment with cvt_pk + bpermute (no LDS round-trip).
__global__ __launch_bounds__(256) void attn_k(const uint16_t* __restrict__ Qf,
                                              const uint16_t* __restrict__ XKV,
                                              const uint16_t* __restrict__ VT,
                                              const float* __restrict__ mask,
                                              const uint32_t* __restrict__ flag,
                                              uint16_t* __restrict__ O32) {
  __shared__ __attribute__((aligned(16))) uint16_t Ks[2][64 * 32];
  __shared__ __attribute__((aligned(16))) uint16_t Vs[2][32 * 64];
  const int tid = threadIdx.x;
  const int lane = tid & 63, w = tid >> 6;
  const int lo = lane & 15, g = lane >> 4;
  const int bid = blockIdx.x;
  const int lb = (bid & 7) * 128 + (bid >> 3); // XCD-chunked: 128 logical blocks/XCD
  const int qt = lb & 31, h = (lb >> 5) & 15, b = lb >> 9;
  const int q0 = qt * 64 + w * 16;
  const bool trivial = (*flag != 0u);
  const float LOG2E = 1.4426950408889634f;

  short8 qf = *(const short8*)(Qf + ((size_t)(b * 2048 + q0 + lo)) * 512 + h * 32 + g * 8);

  // staging source addresses (per thread)
  const int tc = w * 64 + lane;            // chunk 0..255 (16B chunks)
  const int rK = tc >> 2, cK = tc & 3;     // K: 64 rows x 64B, linear
  const uint16_t* Ksrc = XKV + ((size_t)(b * 2048 + rK)) * 1024 + h * 32 + cK * 8;
  const int fV = tc >> 3, sV = tc & 7, cV = (sV - fV) & 7; // V: 32 rows x 128B, +row swizzle
  const uint16_t* Vsrc = VT + ((size_t)(b * 512 + h * 32 + fV)) * 2048 + cV * 8;

  float m = -1e30f, s = 0.f;
  floatx4 acc0 = {0.f, 0.f, 0.f, 0.f}, acc1 = {0.f, 0.f, 0.f, 0.f};
  const floatx4 zf = {0.f, 0.f, 0.f, 0.f};

  __builtin_amdgcn_global_load_lds((const AS1 uint32_t*)Ksrc,
                                   (AS3 uint32_t*)(&Ks[0][0] + w * 512), 16, 0, 0);
  __builtin_amdgcn_global_load_lds((const AS1 uint32_t*)Vsrc,
                                   (AS3 uint32_t*)(&Vs[0][0] + w * 512), 16, 0, 0);
  __syncthreads();

  int buf = 0;
  for (int t = 0; t < 32; ++t) {
    if (t < 31) {
      const uint16_t* kn = Ksrc + (size_t)(t + 1) * 64 * 1024;
      const uint16_t* vn = Vsrc + (size_t)(t + 1) * 64;
      __builtin_amdgcn_global_load_lds((const AS1 uint32_t*)kn,
                                       (AS3 uint32_t*)(&Ks[buf ^ 1][0] + w * 512), 16, 0, 0);
      __builtin_amdgcn_global_load_lds((const AS1 uint32_t*)vn,
                                       (AS3 uint32_t*)(&Vs[buf ^ 1][0] + w * 512), 16, 0, 0);
    }
    const uint16_t* Kb = &Ks[buf][0];
    const uint16_t* Vb = &Vs[buf][0];
    const int k0 = t * 64;
#pragma unroll
    for (int kh = 0; kh < 2; ++kh) {
      short8 kf0 = *(const short8*)(Kb + (kh * 32 + lo) * 32 + g * 8);
      short8 kf1 = *(const short8*)(Kb + (kh * 32 + 16 + lo) * 32 + g * 8);
      floatx4 s0 = __builtin_amdgcn_mfma_f32_16x16x32_bf16(kf0, qf, zf, 0, 0, 0);
      floatx4 s1 = __builtin_amdgcn_mfma_f32_16x16x32_bf16(kf1, qf, zf, 0, 0, 0);
      if (!trivial) {
        const float* mp = mask + (size_t)(q0 + lo) * 2048 + k0 + kh * 32 + g * 4;
        float4 m0 = *(const float4*)mp;
        float4 m1 = *(const float4*)(mp + 16);
        s0[0] -= (1.f / m0.x - 1.f) * LOG2E; s0[1] -= (1.f / m0.y - 1.f) * LOG2E;
        s0[2] -= (1.f / m0.z - 1.f) * LOG2E; s0[3] -= (1.f / m0.w - 1.f) * LOG2E;
        s1[0] -= (1.f / m1.x - 1.f) * LOG2E; s1[1] -= (1.f / m1.y - 1.f) * LOG2E;
        s1[2] -= (1.f / m1.z - 1.f) * LOG2E; s1[3] -= (1.f / m1.w - 1.f) * LOG2E;
      }
      float tm = fmaxf(fmaxf(fmaxf(s0[0], s0[1]), fmaxf(s0[2], s0[3])),
                       fmaxf(fmaxf(s1[0], s1[1]), fmaxf(s1[2], s1[3])));
      tm = fmaxf(tm, __shfl_xor(tm, 16));
      tm = fmaxf(tm, __shfl_xor(tm, 32));
      float mn = fmaxf(m, tm);
      float f = __builtin_amdgcn_exp2f(m - mn);
      float p0[4], p1[4];
      float ts = 0.f;
#pragma unroll
      for (int r = 0; r < 4; ++r) {
        p0[r] = __builtin_amdgcn_exp2f(s0[r] - mn);
        p1[r] = __builtin_amdgcn_exp2f(s1[r] - mn);
        ts += p0[r] + p1[r];
      }
      ts += __shfl_xor(ts, 16);
      ts += __shfl_xor(ts, 32);
      s = s * f + ts;
      m = mn;
#pragma unroll
      for (int r = 0; r < 4; ++r) { acc0[r] *= f; acc1[r] *= f; }
      // pack P -> bf16 pairs, redistribute to PV B-fragment
      uint32_t u0 = cvtpk(p0[0], p0[1]), u1 = cvtpk(p0[2], p0[3]);
      uint32_t u2 = cvtpk(p1[0], p1[1]), u3 = cvtpk(p1[2], p1[3]);
      int srcA = lo + 16 * ((2 * g) & 3);
      int srcB = lo + 16 * ((2 * g + 1) & 3);
      uint32_t a0 = (uint32_t)__shfl((int)u0, srcA), a2 = (uint32_t)__shfl((int)u2, srcA);
      uint32_t a1 = (uint32_t)__shfl((int)u1, srcA), a3 = (uint32_t)__shfl((int)u3, srcA);
      uint32_t b0 = (uint32_t)__shfl((int)u0, srcB), b2 = (uint32_t)__shfl((int)u2, srcB);
      uint32_t b1 = (uint32_t)__shfl((int)u1, srcB), b3 = (uint32_t)__shfl((int)u3, srcB);
      union { uint32_t u[4]; short8 v; } pf;
      pf.u[0] = (g < 2) ? a0 : a2;
      pf.u[1] = (g < 2) ? a1 : a3;
      pf.u[2] = (g < 2) ? b0 : b2;
      pf.u[3] = (g < 2) ? b1 : b3;
      int vc = (kh * 4 + g + lo) & 7;
      short8 v0 = *(const short8*)(Vb + lo * 64 + vc * 8);
      short8 v1 = *(const short8*)(Vb + (lo + 16) * 64 + vc * 8);
      acc0 = __builtin_amdgcn_mfma_f32_16x16x32_bf16(v0, pf.v, acc0, 0, 0, 0);
      acc1 = __builtin_amdgcn_mfma_f32_16x16x32_bf16(v1, pf.v, acc1, 0, 0, 0);
    }
    __syncthreads();
    buf ^= 1;
  }
  float inv = 1.0f / s;
  uint16_t* Op = O32 + ((size_t)(b * 2048 + q0 + lo)) * 512 + h * 32;
#pragma unroll
  for (int r = 0; r < 4; ++r) {
    Op[g * 4 + r] = f2bf(acc0[r] * inv);
    Op[16 + g * 4 + r] = f2bf(acc1[r] * inv);
  }
}

// ---------------- launch ----------------
extern "C" void kernel_launch(void* const* d_in, const int* in_sizes, int n_in,
                              void* d_out, int out_size, void* d_ws, size_t ws_size,
                              hipStream_t stream) {
  const float* q    = (const float*)d_in[0];
  const float* kv   = (const float*)d_in[1];
  const float* mask = (const float*)d_in[2];
  const float* Wq   = (const float*)d_in[3];
  const float* Wk   = (const float*)d_in[4];
  const float* Wv   = (const float*)d_in[5];
  const float* Wo   = (const float*)d_in[6];

  char* ws = (char*)d_ws;
  uint16_t* qb    = (uint16_t*)(ws);
  uint16_t* kvb   = (uint16_t*)(ws + (16ull << 20));
  uint16_t* Qf    = (uint16_t*)(ws + (32ull << 20));
  uint16_t* XKV   = (uint16_t*)(ws + (36ull << 20));
  uint16_t* VT    = (uint16_t*)(ws + (44ull << 20));
  uint16_t* O32   = (uint16_t*)(ws + (48ull << 20));
  uint16_t* WqFT  = (uint16_t*)(ws + (52ull << 20));
  uint16_t* WkvT  = (uint16_t*)(ws + (54ull << 20));
  uint16_t* WoFT  = (uint16_t*)(ws + (58ull << 20));
  uint32_t* flag  = (uint32_t*)(ws + (60ull << 20));

  const float SCALE2 = 0.08838834764831845f * 1.4426950408889634f;

  flag_init_k<<<1, 64, 0, stream>>>(flag);
  mask_scan_k<<<2048, 256, 0, stream>>>(mask, flag);

  cvt_bf16_k<<<8192, 256, 0, stream>>>(q, qb, 2097152);
  cvt_bf16_k<<<8192, 256, 0, stream>>>(kv, kvb, 2097152);
  fold_wq_t_k<<<1024, 256, 0, stream>>>(Wq, WqFT);
  wkv_t_k<<<2048, 256, 0, stream>>>(Wk, Wv, WkvT);
  wof_t_k<<<1024, 256, 0, stream>>>(Wo, WoFT);

  gemm_bt<uint16_t><<<(4096 / 128) * (512 / 64), 256, 0, stream>>>(qb, WqFT, Qf, 4096, 512, 2048, SCALE2);
  gemm_bt<uint16_t><<<(4096 / 128) * (1024 / 64), 256, 0, stream>>>(kvb, WkvT, XKV, 4096, 1024, 2048, 1.0f);
  v_transpose_k<<<2048, 256, 0, stream>>>(XKV, VT);
  attn_k<<<1024, 256, 0, stream>>>(Qf, XKV, VT, mask, flag, O32);
  gemm_bt<float><<<(4096 / 128) * (2048 / 64), 256, 0, stream>>>(O32, WoFT, (float*)d_out, 4096, 2048, 512, 1.0f);
}

// Round 4
// 197.799 us; speedup vs baseline: 1.3929x; 1.0500x over previous
//
#include <hip/hip_runtime.h>
#include <hip/hip_bf16.h>
#include <stdint.h>

typedef short short8 __attribute__((ext_vector_type(8)));
typedef float floatx4 __attribute__((ext_vector_type(4)));

#define AS1 __attribute__((address_space(1)))
#define AS3 __attribute__((address_space(3)))
#define DEV static __device__ __forceinline__

DEV uint16_t f2bf(float x) {
  union { float f; uint32_t u; } v; v.f = x;
  return (uint16_t)((v.u + 0x7fffu + ((v.u >> 16) & 1u)) >> 16);
}

DEV uint32_t cvtpk(float a, float b) {
  uint32_t r;
  asm("v_cvt_pk_bf16_f32 %0, %1, %2" : "=v"(r) : "v"(a), "v"(b));
  return r;
}

// ---------------- prep kernels ----------------

__global__ __launch_bounds__(256) void cvt_bf16_k(const float* __restrict__ src,
                                                  uint16_t* __restrict__ dst, int n4) {
  int i = blockIdx.x * 256 + threadIdx.x;
  if (i >= n4) return;
  float4 v = ((const float4*)src)[i];
  union { uint16_t u[4]; uint64_t q; } o;
  o.u[0] = f2bf(v.x); o.u[1] = f2bf(v.y); o.u[2] = f2bf(v.z); o.u[3] = f2bf(v.w);
  ((uint64_t*)dst)[i] = o.q;
}

// WqFT[j][k] = sum_{r<4} Wq[k][128*(j>>5)+4*(j&31)+r]   (j<512, k<2048), bf16 transposed
__global__ __launch_bounds__(256) void fold_wq_t_k(const float* __restrict__ Wq,
                                                   uint16_t* __restrict__ WqFT) {
  __shared__ float tile[32][33];
  const int t = threadIdx.x;
  const int j0 = (blockIdx.x / 64) * 32, k0 = (blockIdx.x % 64) * 32;
  {
    const int tj = t & 31, tk8 = t >> 5;
    const int j = j0 + tj;
    const int base = 128 * (j >> 5) + 4 * (j & 31);
    for (int kk = 0; kk < 4; ++kk) {
      int kl = tk8 * 4 + kk;
      float4 w = *(const float4*)(Wq + (size_t)(k0 + kl) * 2048 + base);
      tile[tj][kl] = w.x + w.y + w.z + w.w;
    }
  }
  __syncthreads();
  {
    const int tk = t & 31, tj8 = t >> 5;
    for (int jj = 0; jj < 4; ++jj) {
      int jl = tj8 * 4 + jj;
      WqFT[(size_t)(j0 + jl) * 2048 + k0 + tk] = f2bf(tile[jl][tk]);
    }
  }
}

__global__ __launch_bounds__(256) void wkv_t_k(const float* __restrict__ Wk,
                                               const float* __restrict__ Wv,
                                               uint16_t* __restrict__ WkvT) {
  __shared__ float tile[32][33];
  const int t = threadIdx.x;
  const int j0 = (blockIdx.x / 64) * 32, k0 = (blockIdx.x % 64) * 32;
  const float* src = (j0 < 512) ? Wk : Wv;
  const int jb = (j0 < 512) ? j0 : j0 - 512;
  {
    const int tj = t & 31, tk8 = t >> 5;
    for (int kk = 0; kk < 4; ++kk) {
      int kl = tk8 * 4 + kk;
      tile[tj][kl] = src[(size_t)(k0 + kl) * 512 + jb + tj];
    }
  }
  __syncthreads();
  {
    const int tk = t & 31, tj8 = t >> 5;
    for (int jj = 0; jj < 4; ++jj) {
      int jl = tj8 * 4 + jj;
      WkvT[(size_t)(j0 + jl) * 2048 + k0 + tk] = f2bf(tile[jl][tk]);
    }
  }
}

__global__ __launch_bounds__(256) void wof_t_k(const float* __restrict__ Wo,
                                               uint16_t* __restrict__ WoFT) {
  __shared__ float tile[32][33];
  const int t = threadIdx.x;
  const int n0 = (blockIdx.x / 16) * 32, j0 = (blockIdx.x % 16) * 32;
  {
    const int tn = t & 31, tj8 = t >> 5;
    for (int jj = 0; jj < 4; ++jj) {
      int jl = tj8 * 4 + jj;
      int j = j0 + jl;
      int base = 128 * (j >> 5) + 4 * (j & 31);
      float ssum = 0.f;
      for (int r = 0; r < 4; ++r) ssum += Wo[(size_t)(base + r) * 2048 + n0 + tn];
      tile[tn][jl] = ssum;
    }
  }
  __syncthreads();
  {
    const int tj = t & 31, tn8 = t >> 5;
    for (int nn = 0; nn < 4; ++nn) {
      int nl = tn8 * 4 + nn;
      WoFT[(size_t)(n0 + nl) * 512 + j0 + tj] = f2bf(tile[nl][tj]);
    }
  }
}

// mask triviality flag
__global__ void flag_init_k(uint32_t* f) {
  if (threadIdx.x == 0 && blockIdx.x == 0) *f = 1u;
}
__global__ __launch_bounds__(256) void mask_scan_k(const float* __restrict__ mask,
                                                   uint32_t* __restrict__ f) {
  int i = blockIdx.x * 256 + threadIdx.x;
  const float4* p = (const float4*)mask;
  float4 a = p[i * 2], b = p[i * 2 + 1];
  bool bad = (a.x != 1.f) | (a.y != 1.f) | (a.z != 1.f) | (a.w != 1.f) |
             (b.x != 1.f) | (b.y != 1.f) | (b.z != 1.f) | (b.w != 1.f);
  if (bad) *f = 0u;
}

// ------- bf16 GEMM: C[M,N] = A[M,K] @ BT[N,K]^T, optional batch on BT/C ----------
template <typename OutT, int BM, int BN, int FA, int FB>
__global__ __launch_bounds__(256) void gemm_bt(const uint16_t* __restrict__ A,
                                               const uint16_t* __restrict__ BT,
                                               OutT* __restrict__ C, int M, int N, int K,
                                               float scale, int nbb, long sBT, long sC) {
  constexpr int BK = 64;
  __shared__ __attribute__((aligned(16))) uint16_t As[BM * BK];
  __shared__ __attribute__((aligned(16))) uint16_t Bs[BN * BK];
  const int bb = blockIdx.x / nbb, rb = blockIdx.x % nbb;
  BT += (size_t)bb * sBT;
  C += (size_t)bb * sC;
  const int nbn = N / BN;
  const int m0 = (rb / nbn) * BM;
  const int n0 = (rb % nbn) * BN;
  const int lane = threadIdx.x & 63, wave = threadIdx.x >> 6;
  const int lo = lane & 15, g = lane >> 4;
  const int wm = wave >> 1, wn = wave & 1;
  constexpr int CA = BM / 32, CB = BN / 32;
  floatx4 acc[FA][FB] = {};

  for (int k0 = 0; k0 < K; k0 += BK) {
#pragma unroll
    for (int c = 0; c < CA; ++c) {
      int slot = (wave * CA + c) * 64 + lane;
      int row = slot >> 3, col = (slot & 7) * 8;
      __builtin_amdgcn_global_load_lds((const AS1 uint32_t*)(A + (size_t)(m0 + row) * K + k0 + col),
                                       (AS3 uint32_t*)(As + (size_t)(wave * CA + c) * 512), 16, 0, 0);
    }
#pragma unroll
    for (int c = 0; c < CB; ++c) {
      int slot = (wave * CB + c) * 64 + lane;
      int row = slot >> 3, col = (slot & 7) * 8;
      __builtin_amdgcn_global_load_lds((const AS1 uint32_t*)(BT + (size_t)(n0 + row) * K + k0 + col),
                                       (AS3 uint32_t*)(Bs + (size_t)(wave * CB + c) * 512), 16, 0, 0);
    }
    __syncthreads();
#pragma unroll
    for (int kk = 0; kk < BK; kk += 32) {
      short8 af[FA], bf[FB];
#pragma unroll
      for (int fa = 0; fa < FA; ++fa)
        af[fa] = *(const short8*)&As[(wm * FA * 16 + fa * 16 + lo) * BK + kk + g * 8];
#pragma unroll
      for (int fb = 0; fb < FB; ++fb)
        bf[fb] = *(const short8*)&Bs[(wn * FB * 16 + fb * 16 + lo) * BK + kk + g * 8];
#pragma unroll
      for (int fa = 0; fa < FA; ++fa)
#pragma unroll
        for (int fb = 0; fb < FB; ++fb)
          acc[fa][fb] = __builtin_amdgcn_mfma_f32_16x16x32_bf16(af[fa], bf[fb], acc[fa][fb], 0, 0, 0);
    }
    __syncthreads();
  }
#pragma unroll
  for (int fa = 0; fa < FA; ++fa)
#pragma unroll
    for (int fb = 0; fb < FB; ++fb)
#pragma unroll
      for (int r = 0; r < 4; ++r) {
        int row = m0 + wm * FA * 16 + fa * 16 + g * 4 + r;
        int col = n0 + wn * FB * 16 + fb * 16 + lo;
        if constexpr (sizeof(OutT) == 2)
          C[(size_t)row * N + col] = (OutT)f2bf(acc[fa][fb][r] * scale);
        else
          C[(size_t)row * N + col] = (OutT)(acc[fa][fb][r] * scale);
      }
}

// ---------------- flash attention, d_eff = 32, 4 waves/block ----------------
// Merged 64-kv softmax, defer-max (THR=8 in log2 domain), lane-local partial sum,
// K-tile XOR-swizzled both sides (conflict-free ds_read_b128).
__global__ __launch_bounds__(256) void attn_k(const uint16_t* __restrict__ Qf,
                                              const uint16_t* __restrict__ XK,
                                              const uint16_t* __restrict__ VT,
                                              const float* __restrict__ mask,
                                              const uint32_t* __restrict__ flag,
                                              uint16_t* __restrict__ O32) {
  __shared__ __attribute__((aligned(16))) uint16_t Ks[2][64 * 32];
  __shared__ __attribute__((aligned(16))) uint16_t Vs[2][32 * 64];
  const int tid = threadIdx.x;
  const int lane = tid & 63, w = tid >> 6;
  const int lo = lane & 15, g = lane >> 4;
  const int bid = blockIdx.x;
  const int lb = (bid & 7) * 128 + (bid >> 3); // XCD-chunked (1024 % 8 == 0, bijective)
  const int qt = lb & 31, h = (lb >> 5) & 15, b = lb >> 9;
  const int q0 = qt * 64 + w * 16;
  const bool trivial = (*flag != 0u);
  const float LOG2E = 1.4426950408889634f;

  short8 qf = *(const short8*)(Qf + ((size_t)(b * 2048 + q0 + lo)) * 512 + h * 32 + g * 8);

  // K staging: slot s = w*64+lane (16B units); row=s>>2, phys chunk=s&3,
  // global chunk = phys ^ (row&3) ^ ((row>>2)&3)  [inverse == forward, involution via XOR]
  const int sK = w * 64 + lane;
  const int rK = sK >> 2;
  const int cKg = (sK & 3) ^ (rK & 3) ^ ((rK >> 2) & 3);
  const uint16_t* Ksrc = XK + ((size_t)(b * 2048 + rK)) * 512 + h * 32 + cKg * 8;
  // V staging: row f=s>>3, phys chunk=s&7, global chunk = (phys - f)&7
  const int fV = sK >> 3, cV = ((sK & 7) - fV) & 7;
  const uint16_t* Vsrc = VT + ((size_t)(b * 512 + h * 32 + fV)) * 2048 + cV * 8;

  // per-lane read offsets
  const int swzL = (lo & 3) ^ ((lo >> 2) & 3);
  const int cK = (g ^ swzL) * 8;                 // K read: element offset in a 32-elem row
  const int vA = (((g) + lo) & 7) * 8;           // V read, kv 0..31 half
  const int vB = (((g + 4) + lo) & 7) * 8;       // V read, kv 32..63 half
  const int srcA = lo + 16 * ((2 * g) & 3);
  const int srcB = lo + 16 * ((2 * g + 1) & 3);

  float m = -1e30f, sp = 0.f;
  floatx4 acc0 = {0.f, 0.f, 0.f, 0.f}, acc1 = {0.f, 0.f, 0.f, 0.f};
  const floatx4 zf = {0.f, 0.f, 0.f, 0.f};

  __builtin_amdgcn_global_load_lds((const AS1 uint32_t*)Ksrc,
                                   (AS3 uint32_t*)(&Ks[0][0] + w * 512), 16, 0, 0);
  __builtin_amdgcn_global_load_lds((const AS1 uint32_t*)Vsrc,
                                   (AS3 uint32_t*)(&Vs[0][0] + w * 512), 16, 0, 0);
  __syncthreads();

  int buf = 0;
  for (int t = 0; t < 32; ++t) {
    if (t < 31) {
      __builtin_amdgcn_global_load_lds((const AS1 uint32_t*)(Ksrc + (size_t)(t + 1) * 64 * 512),
                                       (AS3 uint32_t*)(&Ks[buf ^ 1][0] + w * 512), 16, 0, 0);
      __builtin_amdgcn_global_load_lds((const AS1 uint32_t*)(Vsrc + (size_t)(t + 1) * 64),
                                       (AS3 uint32_t*)(&Vs[buf ^ 1][0] + w * 512), 16, 0, 0);
    }
    const uint16_t* Kb = &Ks[buf][0];
    const uint16_t* Vb = &Vs[buf][0];
    const int k0 = t * 64;

    short8 kf0 = *(const short8*)(Kb + (lo) * 32 + cK);
    short8 kf1 = *(const short8*)(Kb + (lo + 16) * 32 + cK);
    short8 kf2 = *(const short8*)(Kb + (lo + 32) * 32 + cK);
    short8 kf3 = *(const short8*)(Kb + (lo + 48) * 32 + cK);
    floatx4 s0 = __builtin_amdgcn_mfma_f32_16x16x32_bf16(kf0, qf, zf, 0, 0, 0);
    floatx4 s1 = __builtin_amdgcn_mfma_f32_16x16x32_bf16(kf1, qf, zf, 0, 0, 0);
    floatx4 s2 = __builtin_amdgcn_mfma_f32_16x16x32_bf16(kf2, qf, zf, 0, 0, 0);
    floatx4 s3 = __builtin_amdgcn_mfma_f32_16x16x32_bf16(kf3, qf, zf, 0, 0, 0);

    if (!trivial) {
      const float* mp = mask + (size_t)(q0 + lo) * 2048 + k0 + g * 4;
      float4 m0v = *(const float4*)(mp);
      float4 m1v = *(const float4*)(mp + 16);
      float4 m2v = *(const float4*)(mp + 32);
      float4 m3v = *(const float4*)(mp + 48);
      s0[0] -= (1.f / m0v.x - 1.f) * LOG2E; s0[1] -= (1.f / m0v.y - 1.f) * LOG2E;
      s0[2] -= (1.f / m0v.z - 1.f) * LOG2E; s0[3] -= (1.f / m0v.w - 1.f) * LOG2E;
      s1[0] -= (1.f / m1v.x - 1.f) * LOG2E; s1[1] -= (1.f / m1v.y - 1.f) * LOG2E;
      s1[2] -= (1.f / m1v.z - 1.f) * LOG2E; s1[3] -= (1.f / m1v.w - 1.f) * LOG2E;
      s2[0] -= (1.f / m2v.x - 1.f) * LOG2E; s2[1] -= (1.f / m2v.y - 1.f) * LOG2E;
      s2[2] -= (1.f / m2v.z - 1.f) * LOG2E; s2[3] -= (1.f / m2v.w - 1.f) * LOG2E;
      s3[0] -= (1.f / m3v.x - 1.f) * LOG2E; s3[1] -= (1.f / m3v.y - 1.f) * LOG2E;
      s3[2] -= (1.f / m3v.z - 1.f) * LOG2E; s3[3] -= (1.f / m3v.w - 1.f) * LOG2E;
    }

    float a0 = fmaxf(fmaxf(s0[0], s0[1]), fmaxf(s0[2], s0[3]));
    float a1 = fmaxf(fmaxf(s1[0], s1[1]), fmaxf(s1[2], s1[3]));
    float a2 = fmaxf(fmaxf(s2[0], s2[1]), fmaxf(s2[2], s2[3]));
    float a3 = fmaxf(fmaxf(s3[0], s3[1]), fmaxf(s3[2], s3[3]));
    float pmax = fmaxf(fmaxf(a0, a1), fmaxf(a2, a3));

    if (!__all(pmax - m <= 8.f)) {
      float tm = pmax;
      tm = fmaxf(tm, __shfl_xor(tm, 16));
      tm = fmaxf(tm, __shfl_xor(tm, 32));
      float mn = fmaxf(m, tm);
      float f = __builtin_amdgcn_exp2f(m - mn);
      sp *= f;
#pragma unroll
      for (int r = 0; r < 4; ++r) { acc0[r] *= f; acc1[r] *= f; }
      m = mn;
    }

    float p0[4], p1[4], p2[4], p3[4];
#pragma unroll
    for (int r = 0; r < 4; ++r) {
      p0[r] = __builtin_amdgcn_exp2f(s0[r] - m);
      p1[r] = __builtin_amdgcn_exp2f(s1[r] - m);
      p2[r] = __builtin_amdgcn_exp2f(s2[r] - m);
      p3[r] = __builtin_amdgcn_exp2f(s3[r] - m);
    }
    sp += ((p0[0] + p0[1]) + (p0[2] + p0[3])) + ((p1[0] + p1[1]) + (p1[2] + p1[3])) +
          ((p2[0] + p2[1]) + (p2[2] + p2[3])) + ((p3[0] + p3[1]) + (p3[2] + p3[3]));

    uint32_t u0 = cvtpk(p0[0], p0[1]), u1 = cvtpk(p0[2], p0[3]);
    uint32_t u2 = cvtpk(p1[0], p1[1]), u3 = cvtpk(p1[2], p1[3]);
    uint32_t u4 = cvtpk(p2[0], p2[1]), u5 = cvtpk(p2[2], p2[3]);
    uint32_t u6 = cvtpk(p3[0], p3[1]), u7 = cvtpk(p3[2], p3[3]);

    union { uint32_t u[4]; short8 v; } pfa, pfb;
    {
      uint32_t x0 = (uint32_t)__shfl((int)u0, srcA), x2 = (uint32_t)__shfl((int)u2, srcA);
      uint32_t x1 = (uint32_t)__shfl((int)u1, srcA), x3 = (uint32_t)__shfl((int)u3, srcA);
      uint32_t y0 = (uint32_t)__shfl((int)u0, srcB), y2 = (uint32_t)__shfl((int)u2, srcB);
      uint32_t y1 = (uint32_t)__shfl((int)u1, srcB), y3 = (uint32_t)__shfl((int)u3, srcB);
      pfa.u[0] = (g < 2) ? x0 : x2;
      pfa.u[1] = (g < 2) ? x1 : x3;
      pfa.u[2] = (g < 2) ? y0 : y2;
      pfa.u[3] = (g < 2) ? y1 : y3;
    }
    {
      uint32_t x4 = (uint32_t)__shfl((int)u4, srcA), x6 = (uint32_t)__shfl((int)u6, srcA);
      uint32_t x5 = (uint32_t)__shfl((int)u5, srcA), x7 = (uint32_t)__shfl((int)u7, srcA);
      uint32_t y4 = (uint32_t)__shfl((int)u4, srcB), y6 = (uint32_t)__shfl((int)u6, srcB);
      uint32_t y5 = (uint32_t)__shfl((int)u5, srcB), y7 = (uint32_t)__shfl((int)u7, srcB);
      pfb.u[0] = (g < 2) ? x4 : x6;
      pfb.u[1] = (g < 2) ? x5 : x7;
      pfb.u[2] = (g < 2) ? y4 : y6;
      pfb.u[3] = (g < 2) ? y5 : y7;
    }

    short8 v0a = *(const short8*)(Vb + lo * 64 + vA);
    short8 v1a = *(const short8*)(Vb + (lo + 16) * 64 + vA);
    short8 v0b = *(const short8*)(Vb + lo * 64 + vB);
    short8 v1b = *(const short8*)(Vb + (lo + 16) * 64 + vB);
    acc0 = __builtin_amdgcn_mfma_f32_16x16x32_bf16(v0a, pfa.v, acc0, 0, 0, 0);
    acc1 = __builtin_amdgcn_mfma_f32_16x16x32_bf16(v1a, pfa.v, acc1, 0, 0, 0);
    acc0 = __builtin_amdgcn_mfma_f32_16x16x32_bf16(v0b, pfb.v, acc0, 0, 0, 0);
    acc1 = __builtin_amdgcn_mfma_f32_16x16x32_bf16(v1b, pfb.v, acc1, 0, 0, 0);

    __syncthreads();
    buf ^= 1;
  }
  float s = sp;
  s += __shfl_xor(s, 16);
  s += __shfl_xor(s, 32);
  float inv = 1.0f / s;
  uint16_t* Op = O32 + ((size_t)(b * 2048 + q0 + lo)) * 512 + h * 32;
#pragma unroll
  for (int r = 0; r < 4; ++r) {
    Op[g * 4 + r] = f2bf(acc0[r] * inv);
    Op[16 + g * 4 + r] = f2bf(acc1[r] * inv);
  }
}

// ---------------- launch ----------------
extern "C" void kernel_launch(void* const* d_in, const int* in_sizes, int n_in,
                              void* d_out, int out_size, void* d_ws, size_t ws_size,
                              hipStream_t stream) {
  const float* q    = (const float*)d_in[0];
  const float* kv   = (const float*)d_in[1];
  const float* mask = (const float*)d_in[2];
  const float* Wq   = (const float*)d_in[3];
  const float* Wk   = (const float*)d_in[4];
  const float* Wv   = (const float*)d_in[5];
  const float* Wo   = (const float*)d_in[6];

  char* ws = (char*)d_ws;
  uint16_t* qb    = (uint16_t*)(ws);                  // 16 MB
  uint16_t* kvb   = (uint16_t*)(ws + (16ull << 20));  // 16 MB
  uint16_t* Qf    = (uint16_t*)(ws + (32ull << 20));  // 4 MB
  uint16_t* XK    = (uint16_t*)(ws + (36ull << 20));  // 4 MB
  uint16_t* VT    = (uint16_t*)(ws + (40ull << 20));  // 8 MB
  uint16_t* O32   = (uint16_t*)(ws + (48ull << 20));  // 4 MB
  uint16_t* WqFT  = (uint16_t*)(ws + (52ull << 20));  // 2 MB
  uint16_t* WkvT  = (uint16_t*)(ws + (54ull << 20));  // 4 MB
  uint16_t* WoFT  = (uint16_t*)(ws + (58ull << 20));  // 2 MB
  uint32_t* flag  = (uint32_t*)(ws + (60ull << 20));

  const float SCALE2 = 0.08838834764831845f * 1.4426950408889634f;

  flag_init_k<<<1, 64, 0, stream>>>(flag);
  mask_scan_k<<<2048, 256, 0, stream>>>(mask, flag);

  cvt_bf16_k<<<8192, 256, 0, stream>>>(q, qb, 2097152);
  cvt_bf16_k<<<8192, 256, 0, stream>>>(kv, kvb, 2097152);
  fold_wq_t_k<<<1024, 256, 0, stream>>>(Wq, WqFT);
  wkv_t_k<<<2048, 256, 0, stream>>>(Wk, Wv, WkvT);
  wof_t_k<<<1024, 256, 0, stream>>>(Wo, WoFT);

  // Q projection (folded, pre-scaled): [4096,512] = qb @ WqFT^T
  gemm_bt<uint16_t, 64, 64, 2, 2><<<512, 256, 0, stream>>>(qb, WqFT, Qf, 4096, 512, 2048,
                                                           SCALE2, 512, 0, 0);
  // K projection: [4096,512] = kvb @ WkvT(K)^T
  gemm_bt<uint16_t, 64, 64, 2, 2><<<512, 256, 0, stream>>>(kvb, WkvT, XK, 4096, 512, 2048,
                                                           1.0f, 512, 0, 0);
  // V projection, written transposed: per batch, VT[b] [512, 2048] = WkvT(V) @ kvb[b]^T
  gemm_bt<uint16_t, 64, 64, 2, 2><<<512, 256, 0, stream>>>(WkvT + 512 * 2048, kvb, VT,
                                                           512, 2048, 2048, 1.0f,
                                                           256, 2048L * 2048, 512L * 2048);
  attn_k<<<1024, 256, 0, stream>>>(Qf, XK, VT, mask, flag, O32);
  // output: [4096,2048] fp32 = O32 @ WoFT^T
  gemm_bt<float, 128, 64, 4, 2><<<1024, 256, 0, stream>>>(O32, WoFT, (float*)d_out,
                                                          4096, 2048, 512, 1.0f, 1024, 0, 0);
}